// Round 4
// baseline (51.062 us; speedup 1.0000x reference)
//
#include <hip/hip_runtime.h>
#include <math.h>

// Problem dims (fixed by the reference)
#define M_COMP  8
#define DIN     1024   // input size = DK = DV
#define HDV     4096   // H * DV
#define HID     1024
#define DTOT    8192   // HID * M
#define NV_ROWS 32768  // M_COMP * HDV
#define NJC     32     // j-chunks for u partials
#define UPART_ELEMS (NJC * NV_ROWS)   // 1M floats = 4 MB

typedef float f32x4 __attribute__((ext_vector_type(4)));

__device__ __forceinline__ float wave_reduce_sum(float v) {
    #pragma unroll
    for (int off = 32; off > 0; off >>= 1)
        v += __shfl_down(v, off, 64);
    return v;
}

// ---------------------------------------------------------------------------
// Fused streaming kernel. The final scalar is bilinear:
//   scalar = sum_{m,i} (p[m,i]+bv[m,i]) * u[m,i] + sum_d (bo-K0)_d c_d + bout
//   p = Wv·x  (independent of Wo),  u[m,i] = sum_j c[m,j]*Wo[m,j,i]
//   c[d] = W[d]^2 * Wout[d]        (independent of Wv)
// Both 134 MB passes are independent -> one grid streams both concurrently.
// 2048 blocks, alternating halves in groups of 8 (both halves on every XCD),
// every wave streams exactly 32 KB (perfect balance, no serial tail).
// ---------------------------------------------------------------------------
__global__ __launch_bounds__(256) void k_stream(
    const float* __restrict__ x, const float* __restrict__ Wv,
    const float* __restrict__ bv, const float* __restrict__ Wo,
    const float* __restrict__ W, const float* __restrict__ Wout,
    float* __restrict__ pbias, float* __restrict__ upart)
{
    const int b    = blockIdx.x;
    const int half = (b >> 3) & 1;
    const int hb   = ((b >> 4) << 3) | (b & 7);   // index within half: 0..1023
    const int wib  = threadIdx.x >> 6;
    const int lane = threadIdx.x & 63;
    const int wv   = hb * 4 + wib;                // 0..4095

    if (half == 0) {
        // ---- p half: 8 consecutive Wv rows per wave (32 KB contiguous) ----
        const int row0 = wv * 8;                  // 0..NV_ROWS-8
        const int m    = row0 >> 12;              // 4096 rows per m
        const float* __restrict__ xr = x + m * DIN;
        f32x4 xv[4];
        #pragma unroll
        for (int it = 0; it < 4; ++it)
            xv[it] = *reinterpret_cast<const f32x4*>(xr + it * 256 + lane * 4);
        const float* __restrict__ wr = Wv + (size_t)row0 * DIN + lane * 4;
        float acc[8] = {0.f, 0.f, 0.f, 0.f, 0.f, 0.f, 0.f, 0.f};
        #pragma unroll
        for (int it = 0; it < 4; ++it) {
            #pragma unroll
            for (int r = 0; r < 8; ++r) {
                const f32x4 w4 = *reinterpret_cast<const f32x4*>(
                    wr + (size_t)r * DIN + it * 256);
                acc[r] += w4.x * xv[it].x + w4.y * xv[it].y +
                          w4.z * xv[it].z + w4.w * xv[it].w;
            }
        }
        #pragma unroll
        for (int r = 0; r < 8; ++r) {
            const float s = wave_reduce_sum(acc[r]);
            if (lane == 0) pbias[row0 + r] = s + bv[row0 + r];
        }
    } else {
        // ---- u half: wave owns (m, j-chunk of 32, i-stripe of 256) ----
        const int m   = wv >> 9;                  // 512 waves per m
        const int rem = wv & 511;
        const int jc  = rem >> 4;                 // 0..31
        const int ic  = rem & 15;                 // 0..15 (adjacent waves ->
        const int d0  = m * HID + jc * 32;        //  adjacent i-stripes)
        const float* __restrict__ base =
            Wo + (size_t)d0 * HDV + ic * 256 + lane * 4;
        f32x4 acc = {0.f, 0.f, 0.f, 0.f};
        #pragma unroll 4
        for (int j = 0; j < 32; ++j) {
            const float w = W[d0 + j];
            const float c = w * w * Wout[d0 + j];
            const f32x4 w4 = *reinterpret_cast<const f32x4*>(
                base + (size_t)j * HDV);
            acc += w4 * c;
        }
        *reinterpret_cast<f32x4*>(
            upart + (size_t)jc * NV_ROWS + m * HDV + ic * 256 + lane * 4) = acc;
    }
}

// ---------------------------------------------------------------------------
// Combine: val[e] = pbias[e] * (sum_jc upart[jc][e]); blocks 0..31 also add
// the (bo-K0)*c constant terms. 128 blocks -> 128 partials (fixed tree).
// ---------------------------------------------------------------------------
__global__ __launch_bounds__(256) void k_comb(
    const float* __restrict__ pbias, const float* __restrict__ upart,
    const float* __restrict__ bo, const float* __restrict__ K0,
    const float* __restrict__ W, const float* __restrict__ Wout,
    float* __restrict__ part2)
{
    const int b = blockIdx.x, t = threadIdx.x;
    const int e = b * 256 + t;                    // 0..NV_ROWS-1
    float u = 0.f;
    #pragma unroll
    for (int jc = 0; jc < NJC; ++jc)
        u += upart[(size_t)jc * NV_ROWS + e];
    float val = pbias[e] * u;
    if (b < DTOT / 256) {                         // 32 blocks cover d
        const int d = b * 256 + t;
        const float w = W[d];
        val += (bo[d] - K0[d]) * w * w * Wout[d];
    }
    val = wave_reduce_sum(val);
    __shared__ float s[4];
    if ((t & 63) == 0) s[t >> 6] = val;
    __syncthreads();
    if (t == 0) part2[b] = s[0] + s[1] + s[2] + s[3];
}

__global__ __launch_bounds__(128) void k_fin(
    const float* __restrict__ part2, const float* __restrict__ bout,
    float* __restrict__ out)
{
    const int t = threadIdx.x;
    float val = part2[t];                         // 128 partials
    val = wave_reduce_sum(val);
    __shared__ float s[2];
    if ((t & 63) == 0) s[t >> 6] = val;
    __syncthreads();
    if (t == 0) out[0] = 1.f / (1.f + expf(-(s[0] + s[1] + bout[0])));
}

// ------------------------- fallback (round-3 path) -------------------------
__global__ __launch_bounds__(256) void k_v4(
    const float* __restrict__ x, const float* __restrict__ Wv,
    const float* __restrict__ bv, float* __restrict__ v_out)
{
    const int wave = (int)((blockIdx.x * blockDim.x + threadIdx.x) >> 6);
    const int lane = threadIdx.x & 63;
    const int row0 = wave * 4;
    const int m    = row0 >> 12;
    const float* __restrict__ xr = x + m * DIN;
    f32x4 xv[4];
    #pragma unroll
    for (int it = 0; it < 4; ++it)
        xv[it] = *reinterpret_cast<const f32x4*>(xr + it * 256 + lane * 4);
    const float* __restrict__ wr = Wv + (size_t)row0 * DIN;
    float acc[4] = {0.f, 0.f, 0.f, 0.f};
    #pragma unroll
    for (int r = 0; r < 4; ++r)
        #pragma unroll
        for (int it = 0; it < 4; ++it) {
            const f32x4 w4 = *reinterpret_cast<const f32x4*>(
                wr + (size_t)r * DIN + it * 256 + lane * 4);
            acc[r] += w4.x * xv[it].x + w4.y * xv[it].y +
                      w4.z * xv[it].z + w4.w * xv[it].w;
        }
    #pragma unroll
    for (int r = 0; r < 4; ++r) {
        const float s = wave_reduce_sum(acc[r]);
        if (lane == 0) v_out[row0 + r] = s + bv[row0 + r];
    }
}

__global__ __launch_bounds__(256) void k_o2(
    const float* __restrict__ v, const float* __restrict__ Wo,
    const float* __restrict__ bo, const float* __restrict__ K0,
    const float* __restrict__ W, const float* __restrict__ Wout,
    float* __restrict__ partials)
{
    const int wave = (int)((blockIdx.x * blockDim.x + threadIdx.x) >> 6);
    const int lane = threadIdx.x & 63;
    const int d0   = wave * 2;
    const int m    = d0 >> 10;
    const float* __restrict__ vr = v + m * HDV;
    const float* __restrict__ wr = Wo + (size_t)d0 * HDV;
    float acc0 = 0.f, acc1 = 0.f;
    #pragma unroll
    for (int it = 0; it < 16; ++it) {
        const int i = it * 256 + lane * 4;
        const f32x4 v4 = *reinterpret_cast<const f32x4*>(vr + i);
        const f32x4 a4 = *reinterpret_cast<const f32x4*>(wr + i);
        const f32x4 b4 = *reinterpret_cast<const f32x4*>(wr + HDV + i);
        acc0 += a4.x * v4.x + a4.y * v4.y + a4.z * v4.z + a4.w * v4.w;
        acc1 += b4.x * v4.x + b4.y * v4.y + b4.z * v4.z + b4.w * v4.w;
    }
    acc0 = wave_reduce_sum(acc0);
    acc1 = wave_reduce_sum(acc1);
    if (lane == 0) {
        const float w0 = W[d0],     c0 = w0 * w0 * Wout[d0];
        const float w1 = W[d0 + 1], c1 = w1 * w1 * Wout[d0 + 1];
        partials[wave] = (acc0 + bo[d0]     - K0[d0])     * c0 +
                         (acc1 + bo[d0 + 1] - K0[d0 + 1]) * c1;
    }
}

__global__ __launch_bounds__(256) void k_fin4096(
    const float* __restrict__ partials, const float* __restrict__ bout,
    float* __restrict__ out)
{
    const int t = threadIdx.x;
    float acc = 0.f;
    #pragma unroll
    for (int k = 0; k < 4096 / 256; ++k)
        acc += partials[t + k * 256];
    acc = wave_reduce_sum(acc);
    __shared__ float s[4];
    if ((t & 63) == 0) s[t >> 6] = acc;
    __syncthreads();
    if (t == 0)
        out[0] = 1.f / (1.f + expf(-(s[0] + s[1] + s[2] + s[3] + bout[0])));
}

extern "C" void kernel_launch(void* const* d_in, const int* in_sizes, int n_in,
                              void* d_out, int out_size, void* d_ws, size_t ws_size,
                              hipStream_t stream) {
    // setup_inputs order:
    // 0:x 1:Wq 2:bq 3:Wk 4:bk 5:Wv 6:bv 7:Wo 8:bo 9:K 10:W 11:Wout 12:bout
    const float* x    = (const float*)d_in[0];
    const float* Wv   = (const float*)d_in[5];
    const float* bv   = (const float*)d_in[6];
    const float* Wo   = (const float*)d_in[7];
    const float* bo   = (const float*)d_in[8];
    const float* K    = (const float*)d_in[9];   // only row 0: argmin(cumsum(>=0)) == 0
    const float* W    = (const float*)d_in[10];
    const float* Wout = (const float*)d_in[11];
    const float* bout = (const float*)d_in[12];
    float* out = (float*)d_out;

    // ws layout: pbias (32768) | upart (32*32768) | part2 (128)
    const size_t need = ((size_t)NV_ROWS + UPART_ELEMS + 128) * sizeof(float);
    float* p_ws = (float*)d_ws;

    if (ws_size >= need) {
        float* u_ws  = p_ws + NV_ROWS;
        float* part2 = u_ws + UPART_ELEMS;
        k_stream<<<2048, 256, 0, stream>>>(x, Wv, bv, Wo, W, Wout, p_ws, u_ws);
        k_comb<<<128, 256, 0, stream>>>(p_ws, u_ws, bo, K, W, Wout, part2);
        k_fin<<<1, 128, 0, stream>>>(part2, bout, out);
    } else {
        // round-3 fallback
        float* pr = p_ws + NV_ROWS;
        k_v4<<<NV_ROWS / 16, 256, 0, stream>>>(x, Wv, bv, p_ws);
        k_o2<<<DTOT / 8, 256, 0, stream>>>(p_ws, Wo, bo, K, W, Wout, pr);
        k_fin4096<<<1, 256, 0, stream>>>(pr, bout, out);
    }
}